// Round 5
// baseline (139.360 us; speedup 1.0000x reference)
//
#include <hip/hip_runtime.h>
#include <math.h>

#define VN_EPS   1e-6f
#define NEG      0.2f
#define POS      0.8f   // 1 - NEG

typedef float v2f __attribute__((ext_vector_type(2)));
typedef float v4f __attribute__((ext_vector_type(4)));

// ---- DPP 16-lane (row) reductions: VALU-only, HW-verified R3-R8 ------------
template <int CTRL>
__device__ __forceinline__ float dpp_add(float v) {
    int s = __builtin_amdgcn_update_dpp(0, __float_as_int(v), CTRL, 0xf, 0xf, true);
    return v + __int_as_float(s);
}
__device__ __forceinline__ float row16_allsum(float v) {
    v = dpp_add<0x128>(v);  // row_ror:8
    v = dpp_add<0x124>(v);  // row_ror:4
    v = dpp_add<0x122>(v);  // row_ror:2
    v = dpp_add<0x121>(v);  // row_ror:1
    return v;
}
__device__ __forceinline__ float row16_sum15(float v) {
    v = dpp_add<0x118>(v);  // row_shr:8
    v = dpp_add<0x114>(v);  // row_shr:4
    v = dpp_add<0x112>(v);  // row_shr:2
    v = dpp_add<0x111>(v);  // row_shr:1
    return v;
}
// lane <-> lane^16 exchange (BitMode: xor=16, and=0x1F; intra-32 only)
__device__ __forceinline__ float swz_xor16(float v) {
    return __int_as_float(__builtin_amdgcn_ds_swizzle(__float_as_int(v), 0x401F));
}
// reduce over the 4 og-quarters at fixed k: lane^16 (DS swizzle) then lane^32
// via v_permlane32_swap (VALU on gfx950; halves the DS cost of this reduce).
__device__ __forceinline__ float og4_reduce(float v) {
    v += swz_xor16(v);
#if __has_builtin(__builtin_amdgcn_permlane32_swap)
    auto r = __builtin_amdgcn_permlane32_swap(__float_as_uint(v), __float_as_uint(v),
                                              false, false);
    v = __uint_as_float(r[0]) + __uint_as_float(r[1]);
#else
    v += __shfl_xor(v, 32, 64);
#endif
    return v;
}

// R15: PIPE REBALANCE. R14 (64 lanes/point, no cap) killed the spill
// (FETCH 1.9MB / WRITE 12MB) but ran 49us at VALUBusy ~70%: instruction
// accounting shows ~210 DS-pipe insts/wave (score weights 40, og-reduce 16,
// fold swb broadcasts 96, sfeat traffic ~60) ~= 33-38us on the shared per-CU
// DS pipe — DS was the bottleneck, VMEM idle (3.6% HBM, weights L1-fit).
// Fixes: (1) fold weights read from GLOBAL (L1) instead of LDS — 96 DS -> 96
// VMEM; (2) score-net weights packed [o][8] + swh1 rows as b128 — 40 -> 16
// DS; (3) og-reduce ^32 leg via v_permlane32_swap (VALU) — 16 -> 8 DS.
// DS ~210 -> ~95/wave; VALU/DS/VMEM roughly balanced and overlapping.
// NOTE (R6): scores sc[] are PER-NEIGHBOR — never dedup the fold across k.
// NOTE (R9): the fold must stay fp32 (normalize amplifies bf16 quantization).
// NOTE (R11-R13): never set a min-waves launch bound on this kernel.
__global__ __launch_bounds__(256) void areconv_all(
    const float* __restrict__ q_pts,    // [N,3]
    const float* __restrict__ s_pts,    // [N2,3]
    const int*   __restrict__ nbr,      // [N,16]
    const float* __restrict__ wb,       // [3,256]
    const float* __restrict__ w_vn,     // [3,16]
    const float* __restrict__ wd_vn,    // [3,16]
    const float* __restrict__ w_h1,     // [16,8]
    const float* __restrict__ w_h2,     // [8,8]
    const float* __restrict__ b_h2,     // [8]
    const float* __restrict__ wd_relu,  // [32,32]
    const float* __restrict__ w_un,     // [32,64]
    const float* __restrict__ wd_un,    // [32,64]
    float* __restrict__ out,            // [N,64,3]
    int N)
{
    const float BN_SCALE = 0.999994993f;  // float32(1/sqrt(1+1e-5))

    // packed score-net weights: row o = {wv0,wv1,wv2,wd0,wd1,wd2,0,0}
    __shared__ __align__(16) float sw_sc[16][8];
    __shared__ __align__(16) float swh1 [16][8];   // w_h1 rows (contiguous)
    // per-point hand-off buffers; wave-private (index wv), intra-wave traffic
    __shared__ __align__(16) float sfeat [4][3][32];
    __shared__ __align__(16) float sfeat2[4][3][32];

    const int tid = threadIdx.x;
    if (tid < 128) {
        const int o = tid >> 3, j = tid & 7;
        sw_sc[o][j] = (j < 3) ? w_vn[j * 16 + o]
                    : ((j < 6) ? wd_vn[(j - 3) * 16 + o] : 0.f);
        swh1[o][j] = w_h1[tid];
    }
    __syncthreads();   // only barrier in the kernel

    const int wv   = tid >> 6;        // point slot in block (0..3)
    const int lane = tid & 63;
    const int og   = lane >> 4;       // quarter 0..3 (DPP row)
    const int k    = lane & 15;       // neighbor index
    int n = blockIdx.x * 4 + wv;
    n = (n < N) ? n : (N - 1);        // N=16000 -> never clamps

    // ---- gather + center + cross -> local frame L[c][d] ------------------
    // (all 4 quarters redundantly gather the same 16 neighbors; L1-served)
    const float qx = q_pts[n * 3 + 0];
    const float qy = q_pts[n * 3 + 1];
    const float qz = q_pts[n * 3 + 2];
    const int   id = nbr[n * 16 + k];
    const float px = s_pts[id * 3 + 0] - qx;
    const float py = s_pts[id * 3 + 1] - qy;
    const float pz = s_pts[id * 3 + 2] - qz;

    const float cx = row16_allsum(px) * 0.0625f;
    const float cy = row16_allsum(py) * 0.0625f;
    const float cz = row16_allsum(pz) * 0.0625f;

    const float rx = py * cz - pz * cy;
    const float ry = pz * cx - px * cz;
    const float rz = px * cy - py * cx;

    const float L[3][3] = {{px, py, pz}, {cx, cy, cz}, {rx, ry, rz}};

    // ---- score net: quarter does 4 of the 16 o's, reduce over og ---------
    v4f t0123 = {0.f, 0.f, 0.f, 0.f}, t4567 = t0123;
#pragma unroll 1
    for (int o4 = 0; o4 < 4; ++o4) {
        const int o = og * 4 + o4;
        const v4f wa  = *(const v4f*)&sw_sc[o][0];   // wv0,wv1,wv2,wd0
        const v2f wb2 = *(const v2f*)&sw_sc[o][4];   // wd1,wd2
        const float wv0 = wa[0], wv1 = wa[1], wv2 = wa[2];
        const float wd0 = wa[3], wd1 = wb2[0], wd2 = wb2[1];
        float pv[3], dv[3];
        float dot = 0.f, dsq = 0.f;
#pragma unroll
        for (int d = 0; d < 3; ++d) {
            const float pp = BN_SCALE * (L[0][d] * wv0 + L[1][d] * wv1 + L[2][d] * wv2);
            const float dd = L[0][d] * wd0 + L[1][d] * wd1 + L[2][d] * wd2;
            pv[d] = pp; dv[d] = dd;
            dot += pp * dd;
            dsq += dd * dd;
        }
        const float f = dot * __builtin_amdgcn_rcpf(dsq + VN_EPS);
        float acc = 0.f;
#pragma unroll
        for (int d = 0; d < 3; ++d) {
            const float corr = pv[d] - f * dv[d];
            const float sel  = (dot >= 0.f) ? pv[d] : corr;
            const float a    = NEG * pv[d] + POS * sel;
            acc += a * a;
        }
        const float s = __builtin_amdgcn_sqrtf(acc);
        t0123 += s * (*(const v4f*)&swh1[o][0]);
        t4567 += s * (*(const v4f*)&swh1[o][4]);
    }
    // sum the 4 quarters' partials at fixed k (partner lanes share k)
#pragma unroll
    for (int e = 0; e < 4; ++e) {
        t0123[e] = og4_reduce(t0123[e]);
        t4567[e] = og4_reduce(t4567[e]);
    }

    float tt[8];
#pragma unroll
    for (int e = 0; e < 4; ++e) {
        tt[e]     = fmaxf(t0123[e] * BN_SCALE, 0.f);
        tt[4 + e] = fmaxf(t4567[e] * BN_SCALE, 0.f);
    }

    // ---- 8->8 conv + bias, softmax (per-k; w_h2/b_h2 uniform -> SGPR) ----
    float sc[8];
    float mx = -1e30f;
#pragma unroll
    for (int op = 0; op < 4; ++op) {
        v2f u = *(const v2f*)&b_h2[2 * op];
#pragma unroll
        for (int c = 0; c < 8; ++c)
            u += tt[c] * (*(const v2f*)&w_h2[c * 8 + 2 * op]);
        sc[2 * op + 0] = u[0];
        sc[2 * op + 1] = u[1];
        mx = fmaxf(mx, fmaxf(u[0], u[1]));
    }
    float se = 0.f;
#pragma unroll
    for (int o = 0; o < 8; ++o) { sc[o] = __expf(sc[o] - mx); se += sc[o]; }
    const float inv_se = __builtin_amdgcn_rcpf(se);
#pragma unroll
    for (int o = 0; o < 8; ++o) sc[o] *= inv_se;

    // ---- kernel-point correlation: quarter folds its 8 h's, v2f chunks.
    //      Weights straight from GLOBAL wb (3KB, L1-resident; quarter-
    //      uniform addresses -> 32B/inst coalesced broadcast) --------------
#pragma unroll 1
    for (int gi = 0; gi < 4; ++gi) {
        const int hb = og * 8 + gi * 2;
        const float* wp = wb + hb;
        v2f W0 = sc[0] * (*(const v2f*)&wp[0]);
        v2f W1 = sc[0] * (*(const v2f*)&wp[256]);
        v2f W2 = sc[0] * (*(const v2f*)&wp[512]);
#pragma unroll
        for (int s = 1; s < 8; ++s) {   // full unroll: sc[] stays in regs
            const float sv = sc[s];
            W0 += sv * (*(const v2f*)&wp[s * 32]);
            W1 += sv * (*(const v2f*)&wp[256 + s * 32]);
            W2 += sv * (*(const v2f*)&wp[512 + s * 32]);
        }
        v2f V0 = L[0][0] * W0 + L[1][0] * W1 + L[2][0] * W2;
        v2f V1 = L[0][1] * W0 + L[1][1] * W1 + L[2][1] * W2;
        v2f V2 = L[0][2] * W0 + L[1][2] * W1 + L[2][2] * W2;
        const v2f vv = V0 * V0 + V1 * V1 + V2 * V2;
#pragma unroll
        for (int e = 0; e < 2; ++e) {
            const float inn = __builtin_amdgcn_rsqf(fmaxf(vv[e], 1e-24f)) * 0.0625f;
            V0[e] = row16_sum15(V0[e] * inn);
            V1[e] = row16_sum15(V1[e] * inn);
            V2[e] = row16_sum15(V2[e] * inn);
        }
        if (k == 15) {   // 4 writer lanes per wave, disjoint h ranges
            *(v2f*)&sfeat[wv][0][hb] = V0;
            *(v2f*)&sfeat[wv][1][hb] = V1;
            *(v2f*)&sfeat[wv][2][hb] = V2;
        }
    }
    // intra-wave LDS write->read from here on (in-order DS pipe, no barrier)

    // ---- VNLeakyReLU(32->32): lane owns channel oo (halves redundant) ----
    const int oo = lane & 31;
    {
        float D0 = 0.f, D1 = 0.f, D2 = 0.f;
#pragma unroll 1
        for (int hq = 0; hq < 8; ++hq) {
            const v4f f0 = *(const v4f*)&sfeat[wv][0][hq * 4];
            const v4f f1 = *(const v4f*)&sfeat[wv][1][hq * 4];
            const v4f f2 = *(const v4f*)&sfeat[wv][2][hq * 4];
#pragma unroll
            for (int e = 0; e < 4; ++e) {
                const float w = wd_relu[(hq * 4 + e) * 32 + oo];
                D0 += f0[e] * w;
                D1 += f1[e] * w;
                D2 += f2[e] * w;
            }
        }
        const float p0 = sfeat[wv][0][oo];
        const float p1 = sfeat[wv][1][oo];
        const float p2 = sfeat[wv][2][oo];
        const float dot = p0 * D0 + p1 * D1 + p2 * D2;
        const float dsq = D0 * D0 + D1 * D1 + D2 * D2;
        const float f   = dot * __builtin_amdgcn_rcpf(dsq + VN_EPS);
        const bool  pos = (dot >= 0.f);
        if (lane < 32) {   // one writer per channel
            sfeat2[wv][0][oo] = NEG * p0 + POS * (pos ? p0 : (p0 - f * D0));
            sfeat2[wv][1][oo] = NEG * p1 + POS * (pos ? p1 : (p1 - f * D1));
            sfeat2[wv][2][oo] = NEG * p2 + POS * (pos ? p2 : (p2 - f * D2));
        }
    }

    // ---- VNLinearLeakyReLU(32->64): lane owns output channel o = lane ----
    {
        float AU0 = 0.f, AU1 = 0.f, AU2 = 0.f;
        float AV0 = 0.f, AV1 = 0.f, AV2 = 0.f;
#pragma unroll 1
        for (int hq = 0; hq < 8; ++hq) {
            const v4f f0 = *(const v4f*)&sfeat2[wv][0][hq * 4];
            const v4f f1 = *(const v4f*)&sfeat2[wv][1][hq * 4];
            const v4f f2 = *(const v4f*)&sfeat2[wv][2][hq * 4];
#pragma unroll
            for (int e = 0; e < 4; ++e) {
                const float wu = w_un [(hq * 4 + e) * 64 + lane];
                const float wd = wd_un[(hq * 4 + e) * 64 + lane];
                AU0 += f0[e] * wu; AU1 += f1[e] * wu; AU2 += f2[e] * wu;
                AV0 += f0[e] * wd; AV1 += f1[e] * wd; AV2 += f2[e] * wd;
            }
        }
        const float u0 = AU0 * BN_SCALE;
        const float u1 = AU1 * BN_SCALE;
        const float u2 = AU2 * BN_SCALE;
        const float dot = u0 * AV0 + u1 * AV1 + u2 * AV2;
        const float dsq = AV0 * AV0 + AV1 * AV1 + AV2 * AV2;
        const float f   = dot * __builtin_amdgcn_rcpf(dsq + VN_EPS);
        const bool  pos = (dot >= 0.f);
        const float O0 = NEG * u0 + POS * (pos ? u0 : (u0 - f * AV0));
        const float O1 = NEG * u1 + POS * (pos ? u1 : (u1 - f * AV1));
        const float O2 = NEG * u2 + POS * (pos ? u2 : (u2 - f * AV2));
        // lane o writes out[n, o, 0..2]; 64 lanes cover the 192-float slab.
        // (12 B stride -> only 4-aligned at odd o: scalar stores)
        float* dst = out + (long)n * 192 + 3 * lane;
        dst[0] = O0;
        dst[1] = O1;
        dst[2] = O2;
    }
}

extern "C" void kernel_launch(void* const* d_in, const int* in_sizes, int n_in,
                              void* d_out, int out_size, void* d_ws, size_t ws_size,
                              hipStream_t stream) {
    const float* q_pts   = (const float*)d_in[0];
    const float* s_pts   = (const float*)d_in[1];
    // d_in[2] = s_feats: unused by the reference
    const int*   nbr     = (const int*)  d_in[3];
    const float* wb      = (const float*)d_in[4];
    const float* w_vn    = (const float*)d_in[5];
    const float* wd_vn   = (const float*)d_in[6];
    const float* w_h1    = (const float*)d_in[7];
    const float* w_h2    = (const float*)d_in[8];
    const float* b_h2    = (const float*)d_in[9];
    const float* wd_relu = (const float*)d_in[10];
    const float* w_un    = (const float*)d_in[11];
    const float* wd_un   = (const float*)d_in[12];
    float* out = (float*)d_out;

    const int N = in_sizes[0] / 3;          // q_pts is [N,3]
    const int blocks = (N + 3) / 4;         // 4 points/block, 1 per wave
    areconv_all<<<blocks, 256, 0, stream>>>(
        q_pts, s_pts, nbr, wb, w_vn, wd_vn, w_h1, w_h2, b_h2,
        wd_relu, w_un, wd_un, out, N);
}

// Round 6
// 116.698 us; speedup vs baseline: 1.1942x; 1.1942x over previous
//
#include <hip/hip_runtime.h>
#include <math.h>

#define VN_EPS   1e-6f
#define NEG      0.2f
#define POS      0.8f   // 1 - NEG

typedef float v2f __attribute__((ext_vector_type(2)));
typedef float v4f __attribute__((ext_vector_type(4)));

// ---- DPP 16-lane (row) reductions: VALU-only, HW-verified R3-R8 ------------
template <int CTRL>
__device__ __forceinline__ float dpp_add(float v) {
    int s = __builtin_amdgcn_update_dpp(0, __float_as_int(v), CTRL, 0xf, 0xf, true);
    return v + __int_as_float(s);
}
__device__ __forceinline__ float row16_allsum(float v) {
    v = dpp_add<0x128>(v);  // row_ror:8
    v = dpp_add<0x124>(v);  // row_ror:4
    v = dpp_add<0x122>(v);  // row_ror:2
    v = dpp_add<0x121>(v);  // row_ror:1
    return v;
}
__device__ __forceinline__ float row16_sum15(float v) {
    v = dpp_add<0x118>(v);  // row_shr:8
    v = dpp_add<0x114>(v);  // row_shr:4
    v = dpp_add<0x112>(v);  // row_shr:2
    v = dpp_add<0x111>(v);  // row_shr:1
    return v;
}
// lane <-> lane^16 exchange (BitMode: xor=16, and=0x1F; intra-32 only)
__device__ __forceinline__ float swz_xor16(float v) {
    return __int_as_float(__builtin_amdgcn_ds_swizzle(__float_as_int(v), 0x401F));
}
// v + v[lane^32] at every lane, VALU-only on gfx950 (semantics validated R15:
// bench passed with this path active). Fallback: ds_bpermute via __shfl_xor.
__device__ __forceinline__ float sum_xor32(float v) {
#if __has_builtin(__builtin_amdgcn_permlane32_swap)
    auto r = __builtin_amdgcn_permlane32_swap(__float_as_uint(v), __float_as_uint(v),
                                              false, false);
    return __uint_as_float(r[0]) + __uint_as_float(r[1]);
#else
    return v + __shfl_xor(v, 32, 64);
#endif
}
// reduce over the 4 og-quarters at fixed k: lane^16 (DS swizzle) + lane^32
__device__ __forceinline__ float og4_reduce(float v) {
    v += swz_xor16(v);
    return sum_xor32(v);
}

// R16: REVERT R15's VMEM fold weights (L1 eviction by competing streams ->
// exposed L2 latency, 49->74us regression; hot weights stay in LDS — LDS is
// eviction-proof). Base = R14 (49us, VALU 68%, no spill) + three shavings:
//   1. fold in v4f chunks: 96 ds_b64 -> 48 ds_b128, sfeat writes 12->6,
//      ~40 fewer loop-overhead VALU.
//   2. VNLeakyReLU h-split across wave halves + permlane32 swap-sum combine:
//      DS reads 24->12 b128, wd_relu VMEM 32->16, ~45 fewer VALU.
//   3. og4_reduce ^32 leg on VALU (permlane32_swap, validated R15).
// NOTE (R6): scores sc[] are PER-NEIGHBOR — never dedup the fold across k.
// NOTE (R9): the fold must stay fp32 (normalize amplifies bf16 quantization).
// NOTE (R11-R13): never set a min-waves launch bound on this kernel.
// NOTE (R15): never move small hot weights from LDS to global.
__global__ __launch_bounds__(256) void areconv_all(
    const float* __restrict__ q_pts,    // [N,3]
    const float* __restrict__ s_pts,    // [N2,3]
    const int*   __restrict__ nbr,      // [N,16]
    const float* __restrict__ wb,       // [3,256]
    const float* __restrict__ w_vn,     // [3,16]
    const float* __restrict__ wd_vn,    // [3,16]
    const float* __restrict__ w_h1,     // [16,8]
    const float* __restrict__ w_h2,     // [8,8]
    const float* __restrict__ b_h2,     // [8]
    const float* __restrict__ wd_relu,  // [32,32]
    const float* __restrict__ w_un,     // [32,64]
    const float* __restrict__ wd_un,    // [32,64]
    float* __restrict__ out,            // [N,64,3]
    int N)
{
    const float BN_SCALE = 0.999994993f;  // float32(1/sqrt(1+1e-5))

    // packed score-net weights: row o = {wv0,wv1,wv2,wd0,wd1,wd2,0,0}
    __shared__ __align__(16) float sw_sc[16][8];
    __shared__ __align__(16) float swh1 [16][8];   // w_h1 rows (contiguous)
    __shared__ __align__(16) float swb  [768];     // [3][256] fold weights
    // per-point hand-off buffers; wave-private (index wv), intra-wave traffic
    __shared__ __align__(16) float sfeat [4][3][32];
    __shared__ __align__(16) float sfeat2[4][3][32];

    const int tid = threadIdx.x;
    if (tid < 128) {
        const int o = tid >> 3, j = tid & 7;
        sw_sc[o][j] = (j < 3) ? w_vn[j * 16 + o]
                    : ((j < 6) ? wd_vn[(j - 3) * 16 + o] : 0.f);
        swh1[o][j] = w_h1[tid];
    }
#pragma unroll
    for (int i = 0; i < 3; ++i) swb[tid + 256 * i] = wb[tid + 256 * i];
    __syncthreads();   // only barrier in the kernel

    const int wv   = tid >> 6;        // point slot in block (0..3)
    const int lane = tid & 63;
    const int og   = lane >> 4;       // quarter 0..3 (DPP row)
    const int k    = lane & 15;       // neighbor index
    int n = blockIdx.x * 4 + wv;
    n = (n < N) ? n : (N - 1);        // N=16000 -> never clamps

    // ---- gather + center + cross -> local frame L[c][d] ------------------
    // (all 4 quarters redundantly gather the same 16 neighbors; L1-served)
    const float qx = q_pts[n * 3 + 0];
    const float qy = q_pts[n * 3 + 1];
    const float qz = q_pts[n * 3 + 2];
    const int   id = nbr[n * 16 + k];
    const float px = s_pts[id * 3 + 0] - qx;
    const float py = s_pts[id * 3 + 1] - qy;
    const float pz = s_pts[id * 3 + 2] - qz;

    const float cx = row16_allsum(px) * 0.0625f;
    const float cy = row16_allsum(py) * 0.0625f;
    const float cz = row16_allsum(pz) * 0.0625f;

    const float rx = py * cz - pz * cy;
    const float ry = pz * cx - px * cz;
    const float rz = px * cy - py * cx;

    const float L[3][3] = {{px, py, pz}, {cx, cy, cz}, {rx, ry, rz}};

    // ---- score net: quarter does 4 of the 16 o's, reduce over og ---------
    v4f t0123 = {0.f, 0.f, 0.f, 0.f}, t4567 = t0123;
#pragma unroll 1
    for (int o4 = 0; o4 < 4; ++o4) {
        const int o = og * 4 + o4;
        const v4f wa  = *(const v4f*)&sw_sc[o][0];   // wv0,wv1,wv2,wd0
        const v2f wb2 = *(const v2f*)&sw_sc[o][4];   // wd1,wd2
        const float wv0 = wa[0], wv1 = wa[1], wv2 = wa[2];
        const float wd0 = wa[3], wd1 = wb2[0], wd2 = wb2[1];
        float pv[3], dv[3];
        float dot = 0.f, dsq = 0.f;
#pragma unroll
        for (int d = 0; d < 3; ++d) {
            const float pp = BN_SCALE * (L[0][d] * wv0 + L[1][d] * wv1 + L[2][d] * wv2);
            const float dd = L[0][d] * wd0 + L[1][d] * wd1 + L[2][d] * wd2;
            pv[d] = pp; dv[d] = dd;
            dot += pp * dd;
            dsq += dd * dd;
        }
        const float f = dot * __builtin_amdgcn_rcpf(dsq + VN_EPS);
        float acc = 0.f;
#pragma unroll
        for (int d = 0; d < 3; ++d) {
            const float corr = pv[d] - f * dv[d];
            const float sel  = (dot >= 0.f) ? pv[d] : corr;
            const float a    = NEG * pv[d] + POS * sel;
            acc += a * a;
        }
        const float s = __builtin_amdgcn_sqrtf(acc);
        t0123 += s * (*(const v4f*)&swh1[o][0]);
        t4567 += s * (*(const v4f*)&swh1[o][4]);
    }
    // sum the 4 quarters' partials at fixed k (partner lanes share k)
#pragma unroll
    for (int e = 0; e < 4; ++e) {
        t0123[e] = og4_reduce(t0123[e]);
        t4567[e] = og4_reduce(t4567[e]);
    }

    float tt[8];
#pragma unroll
    for (int e = 0; e < 4; ++e) {
        tt[e]     = fmaxf(t0123[e] * BN_SCALE, 0.f);
        tt[4 + e] = fmaxf(t4567[e] * BN_SCALE, 0.f);
    }

    // ---- 8->8 conv + bias, softmax (per-k; w_h2/b_h2 uniform -> SGPR) ----
    float sc[8];
    float mx = -1e30f;
#pragma unroll
    for (int op = 0; op < 4; ++op) {
        v2f u = *(const v2f*)&b_h2[2 * op];
#pragma unroll
        for (int c = 0; c < 8; ++c)
            u += tt[c] * (*(const v2f*)&w_h2[c * 8 + 2 * op]);
        sc[2 * op + 0] = u[0];
        sc[2 * op + 1] = u[1];
        mx = fmaxf(mx, fmaxf(u[0], u[1]));
    }
    float se = 0.f;
#pragma unroll
    for (int o = 0; o < 8; ++o) { sc[o] = __expf(sc[o] - mx); se += sc[o]; }
    const float inv_se = __builtin_amdgcn_rcpf(se);
#pragma unroll
    for (int o = 0; o < 8; ++o) sc[o] *= inv_se;

    // ---- kernel-point correlation: quarter folds its 8 h's in TWO v4f
    //      chunks (48 ds_read_b128 total; weights LDS-resident) ------------
#pragma unroll 1
    for (int gi = 0; gi < 2; ++gi) {
        const int hb = og * 8 + gi * 4;
        const float* wp = &swb[hb];
        v4f W0 = sc[0] * (*(const v4f*)&wp[0]);
        v4f W1 = sc[0] * (*(const v4f*)&wp[256]);
        v4f W2 = sc[0] * (*(const v4f*)&wp[512]);
#pragma unroll
        for (int s = 1; s < 8; ++s) {   // full unroll: sc[] stays in regs
            const float sv = sc[s];
            W0 += sv * (*(const v4f*)&wp[s * 32]);
            W1 += sv * (*(const v4f*)&wp[256 + s * 32]);
            W2 += sv * (*(const v4f*)&wp[512 + s * 32]);
        }
        v4f V0 = L[0][0] * W0 + L[1][0] * W1 + L[2][0] * W2;
        v4f V1 = L[0][1] * W0 + L[1][1] * W1 + L[2][1] * W2;
        v4f V2 = L[0][2] * W0 + L[1][2] * W1 + L[2][2] * W2;
        const v4f vv = V0 * V0 + V1 * V1 + V2 * V2;
#pragma unroll
        for (int e = 0; e < 4; ++e) {
            const float inn = __builtin_amdgcn_rsqf(fmaxf(vv[e], 1e-24f)) * 0.0625f;
            V0[e] = row16_sum15(V0[e] * inn);
            V1[e] = row16_sum15(V1[e] * inn);
            V2[e] = row16_sum15(V2[e] * inn);
        }
        if (k == 15) {   // 4 writer lanes per wave, disjoint h ranges
            *(v4f*)&sfeat[wv][0][hb] = V0;
            *(v4f*)&sfeat[wv][1][hb] = V1;
            *(v4f*)&sfeat[wv][2][hb] = V2;
        }
    }
    // intra-wave LDS write->read from here on (in-order DS pipe, no barrier)

    // ---- VNLeakyReLU(32->32): h-SPLIT — half0 accumulates h=0..15, half1
    //      h=16..31; permlane32 swap-sum combines. Lane owns channel oo ----
    const int oo = lane & 31;
    {
        const int hh = (lane >> 5) * 16;   // this half's h-base
        float D0 = 0.f, D1 = 0.f, D2 = 0.f;
#pragma unroll
        for (int hq = 0; hq < 4; ++hq) {
            const int hb = hh + hq * 4;
            const v4f f0 = *(const v4f*)&sfeat[wv][0][hb];
            const v4f f1 = *(const v4f*)&sfeat[wv][1][hb];
            const v4f f2 = *(const v4f*)&sfeat[wv][2][hb];
#pragma unroll
            for (int e = 0; e < 4; ++e) {
                const float w = wd_relu[(hb + e) * 32 + oo];
                D0 += f0[e] * w;
                D1 += f1[e] * w;
                D2 += f2[e] * w;
            }
        }
        D0 = sum_xor32(D0);   // full sum over h=0..31 for channel oo
        D1 = sum_xor32(D1);
        D2 = sum_xor32(D2);
        const float p0 = sfeat[wv][0][oo];
        const float p1 = sfeat[wv][1][oo];
        const float p2 = sfeat[wv][2][oo];
        const float dot = p0 * D0 + p1 * D1 + p2 * D2;
        const float dsq = D0 * D0 + D1 * D1 + D2 * D2;
        const float f   = dot * __builtin_amdgcn_rcpf(dsq + VN_EPS);
        const bool  pos = (dot >= 0.f);
        if (lane < 32) {   // one writer per channel
            sfeat2[wv][0][oo] = NEG * p0 + POS * (pos ? p0 : (p0 - f * D0));
            sfeat2[wv][1][oo] = NEG * p1 + POS * (pos ? p1 : (p1 - f * D1));
            sfeat2[wv][2][oo] = NEG * p2 + POS * (pos ? p2 : (p2 - f * D2));
        }
    }

    // ---- VNLinearLeakyReLU(32->64): lane owns output channel o = lane ----
    {
        float AU0 = 0.f, AU1 = 0.f, AU2 = 0.f;
        float AV0 = 0.f, AV1 = 0.f, AV2 = 0.f;
#pragma unroll 1
        for (int hq = 0; hq < 8; ++hq) {
            const v4f f0 = *(const v4f*)&sfeat2[wv][0][hq * 4];
            const v4f f1 = *(const v4f*)&sfeat2[wv][1][hq * 4];
            const v4f f2 = *(const v4f*)&sfeat2[wv][2][hq * 4];
#pragma unroll
            for (int e = 0; e < 4; ++e) {
                const float wu = w_un [(hq * 4 + e) * 64 + lane];
                const float wd = wd_un[(hq * 4 + e) * 64 + lane];
                AU0 += f0[e] * wu; AU1 += f1[e] * wu; AU2 += f2[e] * wu;
                AV0 += f0[e] * wd; AV1 += f1[e] * wd; AV2 += f2[e] * wd;
            }
        }
        const float u0 = AU0 * BN_SCALE;
        const float u1 = AU1 * BN_SCALE;
        const float u2 = AU2 * BN_SCALE;
        const float dot = u0 * AV0 + u1 * AV1 + u2 * AV2;
        const float dsq = AV0 * AV0 + AV1 * AV1 + AV2 * AV2;
        const float f   = dot * __builtin_amdgcn_rcpf(dsq + VN_EPS);
        const bool  pos = (dot >= 0.f);
        const float O0 = NEG * u0 + POS * (pos ? u0 : (u0 - f * AV0));
        const float O1 = NEG * u1 + POS * (pos ? u1 : (u1 - f * AV1));
        const float O2 = NEG * u2 + POS * (pos ? u2 : (u2 - f * AV2));
        // lane o writes out[n, o, 0..2]; 64 lanes cover the 192-float slab.
        // (12 B stride -> only 4-aligned at odd o: scalar stores)
        float* dst = out + (long)n * 192 + 3 * lane;
        dst[0] = O0;
        dst[1] = O1;
        dst[2] = O2;
    }
}

extern "C" void kernel_launch(void* const* d_in, const int* in_sizes, int n_in,
                              void* d_out, int out_size, void* d_ws, size_t ws_size,
                              hipStream_t stream) {
    const float* q_pts   = (const float*)d_in[0];
    const float* s_pts   = (const float*)d_in[1];
    // d_in[2] = s_feats: unused by the reference
    const int*   nbr     = (const int*)  d_in[3];
    const float* wb      = (const float*)d_in[4];
    const float* w_vn    = (const float*)d_in[5];
    const float* wd_vn   = (const float*)d_in[6];
    const float* w_h1    = (const float*)d_in[7];
    const float* w_h2    = (const float*)d_in[8];
    const float* b_h2    = (const float*)d_in[9];
    const float* wd_relu = (const float*)d_in[10];
    const float* w_un    = (const float*)d_in[11];
    const float* wd_un   = (const float*)d_in[12];
    float* out = (float*)d_out;

    const int N = in_sizes[0] / 3;          // q_pts is [N,3]
    const int blocks = (N + 3) / 4;         // 4 points/block, 1 per wave
    areconv_all<<<blocks, 256, 0, stream>>>(
        q_pts, s_pts, nbr, wb, w_vn, wd_vn, w_h1, w_h2, b_h2,
        wd_relu, w_un, wd_un, out, N);
}

// Round 7
// 113.699 us; speedup vs baseline: 1.2257x; 1.0264x over previous
//
#include <hip/hip_runtime.h>
#include <math.h>

#define VN_EPS   1e-6f
#define NEG      0.2f
#define POS      0.8f   // 1 - NEG

typedef float v2f __attribute__((ext_vector_type(2)));
typedef float v4f __attribute__((ext_vector_type(4)));

// ---- DPP 16-lane (row) reductions: VALU-only, HW-verified R3-R8 ------------
template <int CTRL>
__device__ __forceinline__ float dpp_add(float v) {
    int s = __builtin_amdgcn_update_dpp(0, __float_as_int(v), CTRL, 0xf, 0xf, true);
    return v + __int_as_float(s);
}
__device__ __forceinline__ float row16_allsum(float v) {
    v = dpp_add<0x128>(v);  // row_ror:8
    v = dpp_add<0x124>(v);  // row_ror:4
    v = dpp_add<0x122>(v);  // row_ror:2
    v = dpp_add<0x121>(v);  // row_ror:1
    return v;
}
__device__ __forceinline__ float row16_sum15(float v) {
    v = dpp_add<0x118>(v);  // row_shr:8
    v = dpp_add<0x114>(v);  // row_shr:4
    v = dpp_add<0x112>(v);  // row_shr:2
    v = dpp_add<0x111>(v);  // row_shr:1
    return v;
}
// lane <-> lane^16 exchange (BitMode: xor=16, and=0x1F; intra-32 only)
__device__ __forceinline__ float swz_xor16(float v) {
    return __int_as_float(__builtin_amdgcn_ds_swizzle(__float_as_int(v), 0x401F));
}

// R17: og2 — 32 LANES/POINT, 2 points/wave, 8000 waves, NO VGPR CAP.
// Model locked by R14/R16: VALUBusy pins at ~70% for >=4 waves/SIMD ->
// time ~ wave-instruction VOLUME. Volume per point: R10 (16 ln/pt) ~1250
// (but grid 4000 waves starved the machine); R16 og4 ~2500 (softmax+gather
// x4, half-redundant post). og2 is the optimum: grid 8000 waves, softmax/
// gather only x2, og-reduce = ONE xor16 swizzle (the ^32 neighbor is the
// other point - never mix!), VNLeakyReLU zero-redundant (32 ln = 32 ch),
// final layer 2 ch/lane v2f. Volume ~0.6x R16.
//   lane = p*32 + og*16 + k; DPP rows == (p,og) quarters; xor16 stays
//   within each 32-lane half (BitMode and=0x1F).
// NOTE (R6): scores sc[] are PER-NEIGHBOR — never dedup the fold across k.
// NOTE (R9): the fold must stay fp32 (normalize amplifies bf16 quantization).
// NOTE (R11-R13): never set a min-waves launch bound on this kernel.
// NOTE (R15): never move small hot (inner-loop-reused) weights from LDS to
// global; post-phase weights (read once per lane) stay global.
__global__ __launch_bounds__(256) void areconv_all(
    const float* __restrict__ q_pts,    // [N,3]
    const float* __restrict__ s_pts,    // [N2,3]
    const int*   __restrict__ nbr,      // [N,16]
    const float* __restrict__ wb,       // [3,256]
    const float* __restrict__ w_vn,     // [3,16]
    const float* __restrict__ wd_vn,    // [3,16]
    const float* __restrict__ w_h1,     // [16,8]
    const float* __restrict__ w_h2,     // [8,8]
    const float* __restrict__ b_h2,     // [8]
    const float* __restrict__ wd_relu,  // [32,32]
    const float* __restrict__ w_un,     // [32,64]
    const float* __restrict__ wd_un,    // [32,64]
    float* __restrict__ out,            // [N,64,3]
    int N)
{
    const float BN_SCALE = 0.999994993f;  // float32(1/sqrt(1+1e-5))

    // packed score-net weights: row o = {wv0,wv1,wv2,wd0,wd1,wd2,0,0}
    __shared__ __align__(16) float sw_sc[16][8];
    __shared__ __align__(16) float swh1 [16][8];   // w_h1 rows (contiguous)
    __shared__ __align__(16) float swb  [768];     // [3][256] fold weights
    // per-point hand-off buffers; wave-private halves, intra-wave traffic
    __shared__ __align__(16) float sfeat [8][3][32];
    __shared__ __align__(16) float sfeat2[8][3][32];

    const int tid = threadIdx.x;
    if (tid < 128) {
        const int o = tid >> 3, j = tid & 7;
        sw_sc[o][j] = (j < 3) ? w_vn[j * 16 + o]
                    : ((j < 6) ? wd_vn[(j - 3) * 16 + o] : 0.f);
        swh1[o][j] = w_h1[tid];
    }
#pragma unroll
    for (int i = 0; i < 3; ++i) swb[tid + 256 * i] = wb[tid + 256 * i];
    __syncthreads();   // only barrier in the kernel

    const int wv   = tid >> 6;        // wave in block (0..3)
    const int lane = tid & 63;
    const int p    = lane >> 5;       // point-in-wave (0..1)
    const int og   = (lane >> 4) & 1; // half (DPP row = (p,og))
    const int k    = lane & 15;       // neighbor index
    const int bp   = wv * 2 + p;      // point slot in block (0..7)
    int n = blockIdx.x * 8 + bp;
    n = (n < N) ? n : (N - 1);        // N=16000 -> never clamps

    // ---- gather + center + cross -> local frame L[c][d] ------------------
    // (both og halves redundantly gather the same 16 neighbors; L1-served)
    const float qx = q_pts[n * 3 + 0];
    const float qy = q_pts[n * 3 + 1];
    const float qz = q_pts[n * 3 + 2];
    const int   id = nbr[n * 16 + k];
    const float px = s_pts[id * 3 + 0] - qx;
    const float py = s_pts[id * 3 + 1] - qy;
    const float pz = s_pts[id * 3 + 2] - qz;

    const float cx = row16_allsum(px) * 0.0625f;
    const float cy = row16_allsum(py) * 0.0625f;
    const float cz = row16_allsum(pz) * 0.0625f;

    const float rx = py * cz - pz * cy;
    const float ry = pz * cx - px * cz;
    const float rz = px * cy - py * cx;

    const float L[3][3] = {{px, py, pz}, {cx, cy, cz}, {rx, ry, rz}};

    // ---- score net: og half does 8 of the 16 o's, ONE xor16 reduce -------
    v4f t0123 = {0.f, 0.f, 0.f, 0.f}, t4567 = t0123;
#pragma unroll 1
    for (int o8 = 0; o8 < 8; ++o8) {
        const int o = og * 8 + o8;
        const v4f wa  = *(const v4f*)&sw_sc[o][0];   // wv0,wv1,wv2,wd0
        const v2f wb2 = *(const v2f*)&sw_sc[o][4];   // wd1,wd2
        const float wv0 = wa[0], wv1 = wa[1], wv2 = wa[2];
        const float wd0 = wa[3], wd1 = wb2[0], wd2 = wb2[1];
        float pv[3], dv[3];
        float dot = 0.f, dsq = 0.f;
#pragma unroll
        for (int d = 0; d < 3; ++d) {
            const float pp = BN_SCALE * (L[0][d] * wv0 + L[1][d] * wv1 + L[2][d] * wv2);
            const float dd = L[0][d] * wd0 + L[1][d] * wd1 + L[2][d] * wd2;
            pv[d] = pp; dv[d] = dd;
            dot += pp * dd;
            dsq += dd * dd;
        }
        const float f = dot * __builtin_amdgcn_rcpf(dsq + VN_EPS);
        float acc = 0.f;
#pragma unroll
        for (int d = 0; d < 3; ++d) {
            const float corr = pv[d] - f * dv[d];
            const float sel  = (dot >= 0.f) ? pv[d] : corr;
            const float a    = NEG * pv[d] + POS * sel;
            acc += a * a;
        }
        const float s = __builtin_amdgcn_sqrtf(acc);
        t0123 += s * (*(const v4f*)&swh1[o][0]);
        t4567 += s * (*(const v4f*)&swh1[o][4]);
    }
    // sum the 2 halves' partials at fixed (p,k): partner = lane^16
#pragma unroll
    for (int e = 0; e < 4; ++e) {
        t0123[e] += swz_xor16(t0123[e]);
        t4567[e] += swz_xor16(t4567[e]);
    }

    float tt[8];
#pragma unroll
    for (int e = 0; e < 4; ++e) {
        tt[e]     = fmaxf(t0123[e] * BN_SCALE, 0.f);
        tt[4 + e] = fmaxf(t4567[e] * BN_SCALE, 0.f);
    }

    // ---- 8->8 conv + bias, softmax (per-k; w_h2/b_h2 uniform -> SGPR) ----
    float sc[8];
    float mx = -1e30f;
#pragma unroll
    for (int op = 0; op < 4; ++op) {
        v2f u = *(const v2f*)&b_h2[2 * op];
#pragma unroll
        for (int c = 0; c < 8; ++c)
            u += tt[c] * (*(const v2f*)&w_h2[c * 8 + 2 * op]);
        sc[2 * op + 0] = u[0];
        sc[2 * op + 1] = u[1];
        mx = fmaxf(mx, fmaxf(u[0], u[1]));
    }
    float se = 0.f;
#pragma unroll
    for (int o = 0; o < 8; ++o) { sc[o] = __expf(sc[o] - mx); se += sc[o]; }
    const float inv_se = __builtin_amdgcn_rcpf(se);
#pragma unroll
    for (int o = 0; o < 8; ++o) sc[o] *= inv_se;

    // ---- kernel-point correlation: og half folds its 16 h's in FOUR v4f
    //      chunks (weights LDS-resident; R15 law) --------------------------
#pragma unroll 1
    for (int gi = 0; gi < 4; ++gi) {
        const int hb = og * 16 + gi * 4;
        const float* wp = &swb[hb];
        v4f W0 = sc[0] * (*(const v4f*)&wp[0]);
        v4f W1 = sc[0] * (*(const v4f*)&wp[256]);
        v4f W2 = sc[0] * (*(const v4f*)&wp[512]);
#pragma unroll
        for (int s = 1; s < 8; ++s) {   // full unroll: sc[] stays in regs
            const float sv = sc[s];
            W0 += sv * (*(const v4f*)&wp[s * 32]);
            W1 += sv * (*(const v4f*)&wp[256 + s * 32]);
            W2 += sv * (*(const v4f*)&wp[512 + s * 32]);
        }
        v4f V0 = L[0][0] * W0 + L[1][0] * W1 + L[2][0] * W2;
        v4f V1 = L[0][1] * W0 + L[1][1] * W1 + L[2][1] * W2;
        v4f V2 = L[0][2] * W0 + L[1][2] * W1 + L[2][2] * W2;
        const v4f vv = V0 * V0 + V1 * V1 + V2 * V2;
#pragma unroll
        for (int e = 0; e < 4; ++e) {
            const float inn = __builtin_amdgcn_rsqf(fmaxf(vv[e], 1e-24f)) * 0.0625f;
            V0[e] = row16_sum15(V0[e] * inn);
            V1[e] = row16_sum15(V1[e] * inn);
            V2[e] = row16_sum15(V2[e] * inn);
        }
        if (k == 15) {   // lanes 15/31/47/63: disjoint (bp, h-range)
            *(v4f*)&sfeat[bp][0][hb] = V0;
            *(v4f*)&sfeat[bp][1][hb] = V1;
            *(v4f*)&sfeat[bp][2][hb] = V2;
        }
    }
    // intra-wave LDS write->read from here on (in-order DS pipe, no barrier)

    // ---- VNLeakyReLU(32->32): 32 lanes = 32 channels, ZERO redundancy ----
    const int oo = lane & 31;
    {
        float D0 = 0.f, D1 = 0.f, D2 = 0.f;
#pragma unroll 1
        for (int hq = 0; hq < 8; ++hq) {
            const v4f f0 = *(const v4f*)&sfeat[bp][0][hq * 4];
            const v4f f1 = *(const v4f*)&sfeat[bp][1][hq * 4];
            const v4f f2 = *(const v4f*)&sfeat[bp][2][hq * 4];
#pragma unroll
            for (int e = 0; e < 4; ++e) {
                const float w = wd_relu[(hq * 4 + e) * 32 + oo];
                D0 += f0[e] * w;
                D1 += f1[e] * w;
                D2 += f2[e] * w;
            }
        }
        const float p0 = sfeat[bp][0][oo];
        const float p1 = sfeat[bp][1][oo];
        const float p2 = sfeat[bp][2][oo];
        const float dot = p0 * D0 + p1 * D1 + p2 * D2;
        const float dsq = D0 * D0 + D1 * D1 + D2 * D2;
        const float f   = dot * __builtin_amdgcn_rcpf(dsq + VN_EPS);
        const bool  pos = (dot >= 0.f);
        sfeat2[bp][0][oo] = NEG * p0 + POS * (pos ? p0 : (p0 - f * D0));
        sfeat2[bp][1][oo] = NEG * p1 + POS * (pos ? p1 : (p1 - f * D1));
        sfeat2[bp][2][oo] = NEG * p2 + POS * (pos ? p2 : (p2 - f * D2));
    }

    // ---- VNLinearLeakyReLU(32->64): lane owns o = {2oo, 2oo+1} ----------
    {
        v2f AU0 = {0.f, 0.f}, AU1 = AU0, AU2 = AU0;
        v2f AV0 = AU0, AV1 = AU0, AV2 = AU0;
#pragma unroll 1
        for (int hq = 0; hq < 8; ++hq) {
            const v4f f0 = *(const v4f*)&sfeat2[bp][0][hq * 4];
            const v4f f1 = *(const v4f*)&sfeat2[bp][1][hq * 4];
            const v4f f2 = *(const v4f*)&sfeat2[bp][2][hq * 4];
#pragma unroll
            for (int e = 0; e < 4; ++e) {
                const v2f wu = *(const v2f*)&w_un [(hq * 4 + e) * 64 + 2 * oo];
                const v2f wd = *(const v2f*)&wd_un[(hq * 4 + e) * 64 + 2 * oo];
                AU0 += f0[e] * wu; AU1 += f1[e] * wu; AU2 += f2[e] * wu;
                AV0 += f0[e] * wd; AV1 += f1[e] * wd; AV2 += f2[e] * wd;
            }
        }
        float O[6];
#pragma unroll
        for (int j = 0; j < 2; ++j) {
            const float u0 = AU0[j] * BN_SCALE;
            const float u1 = AU1[j] * BN_SCALE;
            const float u2 = AU2[j] * BN_SCALE;
            const float v0 = AV0[j], v1 = AV1[j], v2 = AV2[j];
            const float dot = u0 * v0 + u1 * v1 + u2 * v2;
            const float dsq = v0 * v0 + v1 * v1 + v2 * v2;
            const float f   = dot * __builtin_amdgcn_rcpf(dsq + VN_EPS);
            const bool  pos = (dot >= 0.f);
            O[3 * j + 0] = NEG * u0 + POS * (pos ? u0 : (u0 - f * v0));
            O[3 * j + 1] = NEG * u1 + POS * (pos ? u1 : (u1 - f * v1));
            O[3 * j + 2] = NEG * u2 + POS * (pos ? u2 : (u2 - f * v2));
        }
        // lane oo covers out[n, 2oo..2oo+2, :] = 6 contiguous floats; the
        // point's 32 lanes cover its whole 192-float slab contiguously.
        float* dst = out + (long)n * 192 + 6 * oo;
        *(v2f*)(dst + 0) = *(const v2f*)&O[0];
        *(v2f*)(dst + 2) = *(const v2f*)&O[2];
        *(v2f*)(dst + 4) = *(const v2f*)&O[4];
    }
}

extern "C" void kernel_launch(void* const* d_in, const int* in_sizes, int n_in,
                              void* d_out, int out_size, void* d_ws, size_t ws_size,
                              hipStream_t stream) {
    const float* q_pts   = (const float*)d_in[0];
    const float* s_pts   = (const float*)d_in[1];
    // d_in[2] = s_feats: unused by the reference
    const int*   nbr     = (const int*)  d_in[3];
    const float* wb      = (const float*)d_in[4];
    const float* w_vn    = (const float*)d_in[5];
    const float* wd_vn   = (const float*)d_in[6];
    const float* w_h1    = (const float*)d_in[7];
    const float* w_h2    = (const float*)d_in[8];
    const float* b_h2    = (const float*)d_in[9];
    const float* wd_relu = (const float*)d_in[10];
    const float* w_un    = (const float*)d_in[11];
    const float* wd_un   = (const float*)d_in[12];
    float* out = (float*)d_out;

    const int N = in_sizes[0] / 3;          // q_pts is [N,3]
    const int blocks = (N + 7) / 8;         // 8 points/block, 2 per wave
    areconv_all<<<blocks, 256, 0, stream>>>(
        q_pts, s_pts, nbr, wb, w_vn, wd_vn, w_h1, w_h2, b_h2,
        wd_relu, w_un, wd_un, out, N);
}

// Round 8
// 112.928 us; speedup vs baseline: 1.2341x; 1.0068x over previous
//
#include <hip/hip_runtime.h>
#include <math.h>

#define VN_EPS   1e-6f
#define NEG      0.2f
#define POS      0.8f   // 1 - NEG

typedef float v2f __attribute__((ext_vector_type(2)));
typedef float v4f __attribute__((ext_vector_type(4)));

// ---- DPP 16-lane (row) reductions: VALU-only, HW-verified R3-R8 ------------
template <int CTRL>
__device__ __forceinline__ float dpp_add(float v) {
    int s = __builtin_amdgcn_update_dpp(0, __float_as_int(v), CTRL, 0xf, 0xf, true);
    return v + __int_as_float(s);
}
__device__ __forceinline__ float row16_allsum(float v) {
    v = dpp_add<0x128>(v);  // row_ror:8
    v = dpp_add<0x124>(v);  // row_ror:4
    v = dpp_add<0x122>(v);  // row_ror:2
    v = dpp_add<0x121>(v);  // row_ror:1
    return v;
}
__device__ __forceinline__ float row16_sum15(float v) {
    v = dpp_add<0x118>(v);  // row_shr:8
    v = dpp_add<0x114>(v);  // row_shr:4
    v = dpp_add<0x112>(v);  // row_shr:2
    v = dpp_add<0x111>(v);  // row_shr:1
    return v;
}
// v + v[lane^16] at every lane. Prefer VALU permlane16_swap (same
// two-result-sum pattern as permlane32_swap, validated R15); DS fallback.
__device__ __forceinline__ float sum_xor16(float v) {
#if __has_builtin(__builtin_amdgcn_permlane16_swap)
    auto r = __builtin_amdgcn_permlane16_swap(__float_as_uint(v), __float_as_uint(v),
                                              false, false);
    return __uint_as_float(r[0]) + __uint_as_float(r[1]);
#else
    return v + __int_as_float(
        __builtin_amdgcn_ds_swizzle(__float_as_int(v), 0x401F));
#endif
}

// R18: BANK-CONFLICT SURGERY on the R17 og2 structure (42.2us, 896K
// conflicts — appeared with 2 points/wave: bp stride 96 dwords == 0 mod 32
// banks, and og-paired score rows 64 dwords == same banks).
//   1. sfeat/sfeat2 inner dim 32->36: bp stride 108 == 12 mod 32 -> the two
//      halves' b128 bank-quads disjoint; k==15 write quartet {0,12,16,28}.
//   2. score-weight rows interleaved (o -> 2*(o&7)+og): og pair 8 banks
//      apart -> disjoint quads.
//   3. score og-reduce on VALU via permlane16_swap (-8 DS/wave).
// Model (R14/R16/R17): time ~ max(VALU ~25us, DS ~25us) + non-overlap;
// conflicts sat on the DS critical path.
// NOTE (R6): scores sc[] are PER-NEIGHBOR — never dedup the fold across k.
// NOTE (R9): the fold must stay fp32 (normalize amplifies bf16 quantization).
// NOTE (R11-R13): never set a min-waves launch bound on this kernel.
// NOTE (R15): never move small hot (inner-loop-reused) weights from LDS to
// global; post-phase weights (read once per lane) stay global.
__global__ __launch_bounds__(256) void areconv_all(
    const float* __restrict__ q_pts,    // [N,3]
    const float* __restrict__ s_pts,    // [N2,3]
    const int*   __restrict__ nbr,      // [N,16]
    const float* __restrict__ wb,       // [3,256]
    const float* __restrict__ w_vn,     // [3,16]
    const float* __restrict__ wd_vn,    // [3,16]
    const float* __restrict__ w_h1,     // [16,8]
    const float* __restrict__ w_h2,     // [8,8]
    const float* __restrict__ b_h2,     // [8]
    const float* __restrict__ wd_relu,  // [32,32]
    const float* __restrict__ w_un,     // [32,64]
    const float* __restrict__ wd_un,    // [32,64]
    float* __restrict__ out,            // [N,64,3]
    int N)
{
    const float BN_SCALE = 0.999994993f;  // float32(1/sqrt(1+1e-5))

    // packed score-net weights, ROW-INTERLEAVED: logical row o lives at
    // ip = 2*(o&7) + (o>>3), so the two og-halves' rows are 8 banks apart.
    __shared__ __align__(16) float sw_sc[16][8];   // {wv0..2, wd0..2, 0,0}
    __shared__ __align__(16) float swh1 [16][8];   // w_h1 rows
    __shared__ __align__(16) float swb  [768];     // [3][256] fold weights
    // per-point hand-off buffers; stride 36 (bp stride 108 == 12 mod 32)
    __shared__ __align__(16) float sfeat [8][3][36];
    __shared__ __align__(16) float sfeat2[8][3][36];

    const int tid = threadIdx.x;
    if (tid < 128) {
        const int o = tid >> 3, j = tid & 7;
        const int ip = ((o & 7) << 1) | (o >> 3);   // interleaved row slot
        sw_sc[ip][j] = (j < 3) ? w_vn[j * 16 + o]
                     : ((j < 6) ? wd_vn[(j - 3) * 16 + o] : 0.f);
        swh1[ip][j] = w_h1[tid];
    }
#pragma unroll
    for (int i = 0; i < 3; ++i) swb[tid + 256 * i] = wb[tid + 256 * i];
    __syncthreads();   // only barrier in the kernel

    const int wv   = tid >> 6;        // wave in block (0..3)
    const int lane = tid & 63;
    const int p    = lane >> 5;       // point-in-wave (0..1)
    const int og   = (lane >> 4) & 1; // half (DPP row = (p,og))
    const int k    = lane & 15;       // neighbor index
    const int bp   = wv * 2 + p;      // point slot in block (0..7)
    int n = blockIdx.x * 8 + bp;
    n = (n < N) ? n : (N - 1);        // N=16000 -> never clamps

    // ---- gather + center + cross -> local frame L[c][d] ------------------
    // (both og halves redundantly gather the same 16 neighbors; L1-served)
    const float qx = q_pts[n * 3 + 0];
    const float qy = q_pts[n * 3 + 1];
    const float qz = q_pts[n * 3 + 2];
    const int   id = nbr[n * 16 + k];
    const float px = s_pts[id * 3 + 0] - qx;
    const float py = s_pts[id * 3 + 1] - qy;
    const float pz = s_pts[id * 3 + 2] - qz;

    const float cx = row16_allsum(px) * 0.0625f;
    const float cy = row16_allsum(py) * 0.0625f;
    const float cz = row16_allsum(pz) * 0.0625f;

    const float rx = py * cz - pz * cy;
    const float ry = pz * cx - px * cz;
    const float rz = px * cy - py * cx;

    const float L[3][3] = {{px, py, pz}, {cx, cy, cz}, {rx, ry, rz}};

    // ---- score net: og half does 8 of the 16 o's, ONE xor16 reduce -------
    v4f t0123 = {0.f, 0.f, 0.f, 0.f}, t4567 = t0123;
#pragma unroll 1
    for (int o8 = 0; o8 < 8; ++o8) {
        const int ip = (o8 << 1) | og;               // interleaved row slot
        const v4f wa  = *(const v4f*)&sw_sc[ip][0];  // wv0,wv1,wv2,wd0
        const v2f wb2 = *(const v2f*)&sw_sc[ip][4];  // wd1,wd2
        const float wv0 = wa[0], wv1 = wa[1], wv2 = wa[2];
        const float wd0 = wa[3], wd1 = wb2[0], wd2 = wb2[1];
        float pv[3], dv[3];
        float dot = 0.f, dsq = 0.f;
#pragma unroll
        for (int d = 0; d < 3; ++d) {
            const float pp = BN_SCALE * (L[0][d] * wv0 + L[1][d] * wv1 + L[2][d] * wv2);
            const float dd = L[0][d] * wd0 + L[1][d] * wd1 + L[2][d] * wd2;
            pv[d] = pp; dv[d] = dd;
            dot += pp * dd;
            dsq += dd * dd;
        }
        const float f = dot * __builtin_amdgcn_rcpf(dsq + VN_EPS);
        float acc = 0.f;
#pragma unroll
        for (int d = 0; d < 3; ++d) {
            const float corr = pv[d] - f * dv[d];
            const float sel  = (dot >= 0.f) ? pv[d] : corr;
            const float a    = NEG * pv[d] + POS * sel;
            acc += a * a;
        }
        const float s = __builtin_amdgcn_sqrtf(acc);
        t0123 += s * (*(const v4f*)&swh1[ip][0]);
        t4567 += s * (*(const v4f*)&swh1[ip][4]);
    }
    // sum the 2 halves' partials at fixed (p,k): partner = lane^16 (VALU)
#pragma unroll
    for (int e = 0; e < 4; ++e) {
        t0123[e] = sum_xor16(t0123[e]);
        t4567[e] = sum_xor16(t4567[e]);
    }

    float tt[8];
#pragma unroll
    for (int e = 0; e < 4; ++e) {
        tt[e]     = fmaxf(t0123[e] * BN_SCALE, 0.f);
        tt[4 + e] = fmaxf(t4567[e] * BN_SCALE, 0.f);
    }

    // ---- 8->8 conv + bias, softmax (per-k; w_h2/b_h2 uniform -> SGPR) ----
    float sc[8];
    float mx = -1e30f;
#pragma unroll
    for (int op = 0; op < 4; ++op) {
        v2f u = *(const v2f*)&b_h2[2 * op];
#pragma unroll
        for (int c = 0; c < 8; ++c)
            u += tt[c] * (*(const v2f*)&w_h2[c * 8 + 2 * op]);
        sc[2 * op + 0] = u[0];
        sc[2 * op + 1] = u[1];
        mx = fmaxf(mx, fmaxf(u[0], u[1]));
    }
    float se = 0.f;
#pragma unroll
    for (int o = 0; o < 8; ++o) { sc[o] = __expf(sc[o] - mx); se += sc[o]; }
    const float inv_se = __builtin_amdgcn_rcpf(se);
#pragma unroll
    for (int o = 0; o < 8; ++o) sc[o] *= inv_se;

    // ---- kernel-point correlation: og half folds its 16 h's in FOUR v4f
    //      chunks (weights LDS-resident; R15 law) --------------------------
#pragma unroll 1
    for (int gi = 0; gi < 4; ++gi) {
        const int hb = og * 16 + gi * 4;
        const float* wp = &swb[hb];
        v4f W0 = sc[0] * (*(const v4f*)&wp[0]);
        v4f W1 = sc[0] * (*(const v4f*)&wp[256]);
        v4f W2 = sc[0] * (*(const v4f*)&wp[512]);
#pragma unroll
        for (int s = 1; s < 8; ++s) {   // full unroll: sc[] stays in regs
            const float sv = sc[s];
            W0 += sv * (*(const v4f*)&wp[s * 32]);
            W1 += sv * (*(const v4f*)&wp[256 + s * 32]);
            W2 += sv * (*(const v4f*)&wp[512 + s * 32]);
        }
        v4f V0 = L[0][0] * W0 + L[1][0] * W1 + L[2][0] * W2;
        v4f V1 = L[0][1] * W0 + L[1][1] * W1 + L[2][1] * W2;
        v4f V2 = L[0][2] * W0 + L[1][2] * W1 + L[2][2] * W2;
        const v4f vv = V0 * V0 + V1 * V1 + V2 * V2;
#pragma unroll
        for (int e = 0; e < 4; ++e) {
            const float inn = __builtin_amdgcn_rsqf(fmaxf(vv[e], 1e-24f)) * 0.0625f;
            V0[e] = row16_sum15(V0[e] * inn);
            V1[e] = row16_sum15(V1[e] * inn);
            V2[e] = row16_sum15(V2[e] * inn);
        }
        if (k == 15) {   // lanes 15/31/47/63: banks {0,16,12,28} - disjoint
            *(v4f*)&sfeat[bp][0][hb] = V0;
            *(v4f*)&sfeat[bp][1][hb] = V1;
            *(v4f*)&sfeat[bp][2][hb] = V2;
        }
    }
    // intra-wave LDS write->read from here on (in-order DS pipe, no barrier)

    // ---- VNLeakyReLU(32->32): 32 lanes = 32 channels, ZERO redundancy ----
    const int oo = lane & 31;
    {
        float D0 = 0.f, D1 = 0.f, D2 = 0.f;
#pragma unroll 1
        for (int hq = 0; hq < 8; ++hq) {
            const v4f f0 = *(const v4f*)&sfeat[bp][0][hq * 4];
            const v4f f1 = *(const v4f*)&sfeat[bp][1][hq * 4];
            const v4f f2 = *(const v4f*)&sfeat[bp][2][hq * 4];
#pragma unroll
            for (int e = 0; e < 4; ++e) {
                const float w = wd_relu[(hq * 4 + e) * 32 + oo];
                D0 += f0[e] * w;
                D1 += f1[e] * w;
                D2 += f2[e] * w;
            }
        }
        const float p0 = sfeat[bp][0][oo];
        const float p1 = sfeat[bp][1][oo];
        const float p2 = sfeat[bp][2][oo];
        const float dot = p0 * D0 + p1 * D1 + p2 * D2;
        const float dsq = D0 * D0 + D1 * D1 + D2 * D2;
        const float f   = dot * __builtin_amdgcn_rcpf(dsq + VN_EPS);
        const bool  pos = (dot >= 0.f);
        sfeat2[bp][0][oo] = NEG * p0 + POS * (pos ? p0 : (p0 - f * D0));
        sfeat2[bp][1][oo] = NEG * p1 + POS * (pos ? p1 : (p1 - f * D1));
        sfeat2[bp][2][oo] = NEG * p2 + POS * (pos ? p2 : (p2 - f * D2));
    }

    // ---- VNLinearLeakyReLU(32->64): lane owns o = {2oo, 2oo+1} ----------
    {
        v2f AU0 = {0.f, 0.f}, AU1 = AU0, AU2 = AU0;
        v2f AV0 = AU0, AV1 = AU0, AV2 = AU0;
#pragma unroll 1
        for (int hq = 0; hq < 8; ++hq) {
            const v4f f0 = *(const v4f*)&sfeat2[bp][0][hq * 4];
            const v4f f1 = *(const v4f*)&sfeat2[bp][1][hq * 4];
            const v4f f2 = *(const v4f*)&sfeat2[bp][2][hq * 4];
#pragma unroll
            for (int e = 0; e < 4; ++e) {
                const v2f wu = *(const v2f*)&w_un [(hq * 4 + e) * 64 + 2 * oo];
                const v2f wd = *(const v2f*)&wd_un[(hq * 4 + e) * 64 + 2 * oo];
                AU0 += f0[e] * wu; AU1 += f1[e] * wu; AU2 += f2[e] * wu;
                AV0 += f0[e] * wd; AV1 += f1[e] * wd; AV2 += f2[e] * wd;
            }
        }
        float O[6];
#pragma unroll
        for (int j = 0; j < 2; ++j) {
            const float u0 = AU0[j] * BN_SCALE;
            const float u1 = AU1[j] * BN_SCALE;
            const float u2 = AU2[j] * BN_SCALE;
            const float v0 = AV0[j], v1 = AV1[j], v2 = AV2[j];
            const float dot = u0 * v0 + u1 * v1 + u2 * v2;
            const float dsq = v0 * v0 + v1 * v1 + v2 * v2;
            const float f   = dot * __builtin_amdgcn_rcpf(dsq + VN_EPS);
            const bool  pos = (dot >= 0.f);
            O[3 * j + 0] = NEG * u0 + POS * (pos ? u0 : (u0 - f * v0));
            O[3 * j + 1] = NEG * u1 + POS * (pos ? u1 : (u1 - f * v1));
            O[3 * j + 2] = NEG * u2 + POS * (pos ? u2 : (u2 - f * v2));
        }
        // lane oo covers out[n, 2oo..2oo+2, :] = 6 contiguous floats; the
        // point's 32 lanes cover its whole 192-float slab contiguously.
        float* dst = out + (long)n * 192 + 6 * oo;
        *(v2f*)(dst + 0) = *(const v2f*)&O[0];
        *(v2f*)(dst + 2) = *(const v2f*)&O[2];
        *(v2f*)(dst + 4) = *(const v2f*)&O[4];
    }
}

extern "C" void kernel_launch(void* const* d_in, const int* in_sizes, int n_in,
                              void* d_out, int out_size, void* d_ws, size_t ws_size,
                              hipStream_t stream) {
    const float* q_pts   = (const float*)d_in[0];
    const float* s_pts   = (const float*)d_in[1];
    // d_in[2] = s_feats: unused by the reference
    const int*   nbr     = (const int*)  d_in[3];
    const float* wb      = (const float*)d_in[4];
    const float* w_vn    = (const float*)d_in[5];
    const float* wd_vn   = (const float*)d_in[6];
    const float* w_h1    = (const float*)d_in[7];
    const float* w_h2    = (const float*)d_in[8];
    const float* b_h2    = (const float*)d_in[9];
    const float* wd_relu = (const float*)d_in[10];
    const float* w_un    = (const float*)d_in[11];
    const float* wd_un   = (const float*)d_in[12];
    float* out = (float*)d_out;

    const int N = in_sizes[0] / 3;          // q_pts is [N,3]
    const int blocks = (N + 7) / 8;         // 8 points/block, 2 per wave
    areconv_all<<<blocks, 256, 0, stream>>>(
        q_pts, s_pts, nbr, wb, w_vn, wd_vn, w_h1, w_h2, b_h2,
        wd_relu, w_un, wd_un, out, N);
}